// Round 15
// baseline (39.244 us; speedup 1.0000x reference)
//
#include <hip/hip_runtime.h>
#include <hip/hip_bf16.h>

#define NB 16
#define NN 256
#define NH 8
#define ND 64
#define NT 5
#define HD 512   // NH*ND

typedef __bf16 bf16x8 __attribute__((ext_vector_type(8)));
typedef __bf16 bf16x4 __attribute__((ext_vector_type(4)));
typedef float  f32x4  __attribute__((ext_vector_type(4)));
typedef int    i32x4  __attribute__((ext_vector_type(4)));

__device__ __forceinline__ bf16x8 cvt8(f32x4 a, f32x4 b) {
    bf16x8 r;
    r[0] = (__bf16)a[0]; r[1] = (__bf16)a[1]; r[2] = (__bf16)a[2]; r[3] = (__bf16)a[3];
    r[4] = (__bf16)b[0]; r[5] = (__bf16)b[1]; r[6] = (__bf16)b[2]; r[7] = (__bf16)b[3];
    return r;
}

// fire-and-forget global->LDS: lane l writes LDS[base + l*16]; src addr is per-lane.
__device__ __forceinline__ void stage16(const void* g, void* l) {
    __builtin_amdgcn_global_load_lds(
        (const __attribute__((address_space(1))) void*)g,
        (__attribute__((address_space(3))) void*)l,
        16, 0, 0);
}

// Transpose a[(h*64+dd)*64*5 + e*5 + t] (fp32) -> wt[h][t][e][dd] (bf16).
__global__ void prep_w_kernel(const float* __restrict__ a, __bf16* __restrict__ wt) {
    int idx = blockIdx.x * 256 + threadIdx.x;
    if (idx >= NH * ND * ND * NT) return;
    int t  = idx % NT;
    int e  = (idx / NT) % ND;
    int dd = (idx / (NT * ND)) % ND;
    int h  = idx / (NT * ND * ND);
    wt[(((h * NT + t) * ND + e) * ND) + dd] = (__bf16)a[idx];
}

// ================= fused: block = (b, h, j-quarter); loops 16 i-tiles =================
// No T intermediate. W staged once (DMA); D-frags in registers (fixed per block);
// S/E/P double-buffered; exactly ONE barrier per iteration.
__global__ __launch_bounds__(256, 2) void mhea_fused(
    const float* __restrict__ src, const float* __restrict__ dst,
    const __bf16* __restrict__ wt, const int* __restrict__ edges,
    float* __restrict__ out)
{
    // W: [t][e(64) x 128B], 16B-chunk c holds global chunk c^(e&7)     (40 KB)
    __shared__ alignas(16) __bf16 Wl[NT * ND * ND];
    // S: dbuf rows i(16) x 256B, chunk c holds global c^(i&7)          (2 x 4 KB)
    __shared__ alignas(16) float  Sl[2][16 * ND];
    // E: dbuf rows i(16) x 256B (64 ints), chunk c holds global c^(i&7)(2 x 4 KB)
    __shared__ alignas(16) int    El[2][16 * 64];
    // P: dbuf [t][i(16)][e(64)] bf16, e-idx ^ ((i&7)<<3)               (2 x 10 KB)
    __shared__ alignas(16) __bf16 Pl[2][NT * 16 * ND];

    // XCD-chunked decode: XCD x gets 64 consecutive wgs = 2 complete b's.
    const int bid = blockIdx.x;
    const int wg  = (bid & 7) * 64 + (bid >> 3);    // bijective, 512 = 8*64
    const int b   = wg >> 5;
    const int h   = (wg >> 2) & 7;
    const int jq  = wg & 3;
    const int j0  = jq * 64;

    const int tid = threadIdx.x;
    const int w   = tid >> 6;    // wave 0..3: phase-1 e-tile AND phase-2 j-tile
    const int l   = tid & 63;
    const int il  = l & 15;
    const int kg  = l >> 4;      // lane k-group 0..3

    // ---------------- prologue ----------------
    // D-frags (fixed per block): dst row j = j0 + w*16 + il, via register loads.
    bf16x8 cb0, cb1;
    {
        const float* dp = dst + ((size_t)(b * NN + j0 + w * 16 + il)) * HD + h * ND;
        f32x4 q0 = *reinterpret_cast<const f32x4*>(dp + kg * 8);
        f32x4 q1 = *reinterpret_cast<const f32x4*>(dp + kg * 8 + 4);
        f32x4 q2 = *reinterpret_cast<const f32x4*>(dp + 32 + kg * 8);
        f32x4 q3 = *reinterpret_cast<const f32x4*>(dp + 36 + kg * 8);
        cb0 = cvt8(q0, q1);
        cb1 = cvt8(q2, q3);
    }

    // W staging: 40 x 1KB (10/wave), pre-swizzled source.
    {
        const __bf16* wbase = wt + (size_t)(h * NT) * ND * ND;
        #pragma unroll
        for (int k = 0; k < 10; ++k) {
            const int idx  = w * 10 + k;         // 0..39
            const int t    = idx >> 3;
            const int sub  = idx & 7;
            const int e    = sub * 8 + (l >> 3);
            const int c    = (l & 7) ^ (e & 7);
            stage16(wbase + ((size_t)t * ND + e) * ND + c * 8,
                    &Wl[t * 4096 + sub * 512]);
        }
    }
    // S[0]: 4 x 1KB (1/wave): rows w*4..w*4+3
    {
        const int row = w * 4 + (l >> 4);
        const int c   = (l & 15) ^ (row & 7);
        stage16(src + ((size_t)(b * NN + row)) * HD + h * ND + c * 4,
                &Sl[0][w * 1024 / 4]);
    }
    // E[0]: 4 x 1KB (1/wave): rows w*4..w*4+3 (row = 64 ints = 256B)
    {
        const int row = w * 4 + (l >> 4);
        const int c   = (l & 15) ^ (row & 7);
        stage16(edges + ((size_t)(b * NN + row)) * NN + j0 + c * 4,
                &El[0][w * 256]);
    }

    __syncthreads();   // vmcnt(0) drain: W, S[0], E[0] resident

    // W-frags -> registers once (wave's e-tile = w, all 5 t)
    bf16x8 wa[NT][2];
    #pragma unroll
    for (int t = 0; t < NT; ++t)
        #pragma unroll
        for (int ks = 0; ks < 2; ++ks)
            wa[t][ks] = *reinterpret_cast<const bf16x8*>(
                &Wl[t * 4096 + (w * 16 + il) * ND + (((ks * 4 + kg) ^ (il & 7)) << 3)]);

    // ---------------- main loop: 16 i-tiles, ONE barrier each ----------------
    for (int k = 0; k < 16; ++k) {
        const int cb = k & 1;
        const int nb = cb ^ 1;

        // a) stage next i-tile's src + edges (latency covered by phase 1)
        if (k < 15) {
            const int i1 = (k + 1) * 16;
            {
                const int row = w * 4 + (l >> 4);
                const int c   = (l & 15) ^ (row & 7);
                stage16(src + ((size_t)(b * NN + i1 + row)) * HD + h * ND + c * 4,
                        &Sl[nb][w * 256]);
            }
            {
                const int row = w * 4 + (l >> 4);
                const int c   = (l & 15) ^ (row & 7);
                stage16(edges + ((size_t)(b * NN + i1 + row)) * NN + j0 + c * 4,
                        &El[nb][w * 256]);
            }
        }

        // b) edge int4 for THIS iter (pre-barrier => E dbuf race-free):
        //    lane (il,kg) wants edges[b, i0+il, j0 + w*16 + kg*4 ..+3] = chunk q=w*4+kg
        const i32x4 ce = *reinterpret_cast<const i32x4*>(
            &El[cb][il * 64 + (((w * 4 + kg) ^ (il & 7)) << 2)]);

        // c) phase 1: P_t[i, e-tile w] from S[cb]
        {
            f32x4 a0 = *reinterpret_cast<const f32x4*>(&Sl[cb][il * ND + (((2 * kg + 0) ^ (il & 7)) << 2)]);
            f32x4 a1 = *reinterpret_cast<const f32x4*>(&Sl[cb][il * ND + (((2 * kg + 1) ^ (il & 7)) << 2)]);
            f32x4 a2 = *reinterpret_cast<const f32x4*>(&Sl[cb][il * ND + (((8 + 2 * kg) ^ (il & 7)) << 2)]);
            f32x4 a3 = *reinterpret_cast<const f32x4*>(&Sl[cb][il * ND + (((9 + 2 * kg) ^ (il & 7)) << 2)]);
            bf16x8 bf0 = cvt8(a0, a1);
            bf16x8 bf1 = cvt8(a2, a3);
            #pragma unroll
            for (int t = 0; t < NT; ++t) {
                // A = W^T rows (m=e), B = src (n=i): lane holds e=w*16+kg*4+r, i=il
                f32x4 pacc = {0.f, 0.f, 0.f, 0.f};
                pacc = __builtin_amdgcn_mfma_f32_16x16x32_bf16(wa[t][0], bf0, pacc, 0, 0, 0);
                pacc = __builtin_amdgcn_mfma_f32_16x16x32_bf16(wa[t][1], bf1, pacc, 0, 0, 0);
                bf16x4 pk;
                pk[0] = (__bf16)pacc[0];
                pk[1] = (__bf16)pacc[1];
                pk[2] = (__bf16)pacc[2];
                pk[3] = (__bf16)pacc[3];
                const int elem = (w * 16 + kg * 4) ^ ((il & 7) << 3);
                *reinterpret_cast<bf16x4*>(&Pl[cb][t * 1024 + il * ND + elem]) = pk;
            }
        }

        // d) the one barrier: P[cb] visible to all waves (also drains staging DMA)
        __syncthreads();

        // e) phase 2: S_t = dst_rows . P -> select/mask/leaky -> store
        {
            bf16x8 pa[NT][2];
            #pragma unroll
            for (int t = 0; t < NT; ++t)
                #pragma unroll
                for (int ks = 0; ks < 2; ++ks)
                    pa[t][ks] = *reinterpret_cast<const bf16x8*>(
                        &Pl[cb][t * 1024 + il * ND + (((ks * 4 + kg) ^ (il & 7)) << 3)]);

            f32x4 acc[NT];
            #pragma unroll
            for (int t = 0; t < NT; ++t) {
                acc[t] = (f32x4){0.f, 0.f, 0.f, 0.f};
                // A = dst rows (m=j), B = P (n=i): lane holds j=w*16+kg*4+r, i=il
                acc[t] = __builtin_amdgcn_mfma_f32_16x16x32_bf16(cb0, pa[t][0], acc[t], 0, 0, 0);
                acc[t] = __builtin_amdgcn_mfma_f32_16x16x32_bf16(cb1, pa[t][1], acc[t], 0, 0, 0);
            }

            f32x4 o;
            #pragma unroll
            for (int r = 0; r < 4; ++r) {
                const int ev = ce[r];
                float x;
                if (ev < 0) { x = -1e10f; }
                else {
                    x = (ev == 0) ? acc[0][r]
                      : (ev == 1) ? acc[1][r]
                      : (ev == 2) ? acc[2][r]
                      : (ev == 3) ? acc[3][r]
                      :             acc[4][r];
                }
                o[r] = (x >= 0.f) ? x : 0.2f * x;
            }
            *reinterpret_cast<f32x4*>(
                out + ((size_t)(b * NH + h) * NN + k * 16 + il) * NN
                    + j0 + w * 16 + kg * 4) = o;
        }
        // no second barrier needed: next iter's ph1 writes P[nb] (other buffer),
        // S/E[nb] staging was issued pre-barrier, S/E[cb] re-staged only after
        // the NEXT barrier. All cross-wave hazards separated by one barrier/iter.
    }
}

// ---------------- fallback (ws too small): fused 1-wave kernel, araw path ----------------
__global__ __launch_bounds__(64, 3) void mhea_fused_fallback(
    const float* __restrict__ src, const float* __restrict__ dst,
    const float* __restrict__ araw, const int* __restrict__ edges,
    float* __restrict__ out)
{
    __shared__ __bf16 Plds[NT * 16 * 64];

    const int it = blockIdx.x;
    const int h  = blockIdx.y;
    const int b  = blockIdx.z;
    const int i0 = it * 16;

    const int l  = threadIdx.x & 63;
    const int il = l & 15;
    const int kg = l >> 4;

    const float* dbase = dst + (size_t)b * NN * HD + h * ND;
    const int*   erow  = edges + ((size_t)b * NN + i0 + il) * NN;
    const float* sbase = src + (size_t)(b * NN + i0 + il) * HD + h * ND;

    f32x4 s0 = *reinterpret_cast<const f32x4*>(sbase + kg * 8);
    f32x4 s1 = *reinterpret_cast<const f32x4*>(sbase + kg * 8 + 4);
    f32x4 s2 = *reinterpret_cast<const f32x4*>(sbase + 32 + kg * 8);
    f32x4 s3 = *reinterpret_cast<const f32x4*>(sbase + 36 + kg * 8);
    bf16x8 af0 = cvt8(s0, s1);
    bf16x8 af1 = cvt8(s2, s3);

    #pragma unroll
    for (int t = 0; t < NT; ++t) {
        #pragma unroll
        for (int et = 0; et < 4; ++et) {
            bf16x8 w0, w1;
            #pragma unroll
            for (int jj = 0; jj < 8; ++jj) {
                const int ee = et * 16 + il;
                w0[jj] = (__bf16)araw[((size_t)(h * ND + kg * 8 + jj) * ND + ee) * NT + t];
                w1[jj] = (__bf16)araw[((size_t)(h * ND + kg * 8 + jj + 32) * ND + ee) * NT + t];
            }
            f32x4 pacc = {0.f, 0.f, 0.f, 0.f};
            pacc = __builtin_amdgcn_mfma_f32_16x16x32_bf16(w0, af0, pacc, 0, 0, 0);
            pacc = __builtin_amdgcn_mfma_f32_16x16x32_bf16(w1, af1, pacc, 0, 0, 0);
            bf16x4 pk;
            pk[0] = (__bf16)pacc[0];
            pk[1] = (__bf16)pacc[1];
            pk[2] = (__bf16)pacc[2];
            pk[3] = (__bf16)pacc[3];
            const int elem = (et * 16 + kg * 4) ^ ((il & 7) << 3);
            *reinterpret_cast<bf16x4*>(&Plds[t * 1024 + il * 64 + elem]) = pk;
        }
    }

    bf16x8 pa[NT][2];
    #pragma unroll
    for (int t = 0; t < NT; ++t) {
        #pragma unroll
        for (int ks = 0; ks < 2; ++ks) {
            const int elem = (ks * 32 + kg * 8) ^ ((il & 7) << 3);
            pa[t][ks] = *reinterpret_cast<const bf16x8*>(&Plds[t * 1024 + il * 64 + elem]);
        }
    }

    float* obase = out + (((size_t)(b * NH + h)) * NN + i0 + il) * NN;

    for (int jt = 0; jt < 16; ++jt) {
        const float* np = dbase + (size_t)(jt * 16 + il) * HD + kg * 8;
        f32x4 d0 = *reinterpret_cast<const f32x4*>(np);
        f32x4 d1 = *reinterpret_cast<const f32x4*>(np + 4);
        f32x4 d2 = *reinterpret_cast<const f32x4*>(np + 32);
        f32x4 d3 = *reinterpret_cast<const f32x4*>(np + 36);
        i32x4 ce = *reinterpret_cast<const i32x4*>(erow + jt * 16 + kg * 4);
        const bf16x8 cb0 = cvt8(d0, d1);
        const bf16x8 cb1 = cvt8(d2, d3);
        f32x4 acc[NT];
        #pragma unroll
        for (int t = 0; t < NT; ++t) {
            acc[t] = (f32x4){0.f, 0.f, 0.f, 0.f};
            acc[t] = __builtin_amdgcn_mfma_f32_16x16x32_bf16(cb0, pa[t][0], acc[t], 0, 0, 0);
            acc[t] = __builtin_amdgcn_mfma_f32_16x16x32_bf16(cb1, pa[t][1], acc[t], 0, 0, 0);
        }
        f32x4 o;
        #pragma unroll
        for (int r = 0; r < 4; ++r) {
            const int ev = ce[r];
            float x;
            if (ev < 0) { x = -1e10f; }
            else {
                x = (ev == 0) ? acc[0][r]
                  : (ev == 1) ? acc[1][r]
                  : (ev == 2) ? acc[2][r]
                  : (ev == 3) ? acc[3][r]
                  :             acc[4][r];
            }
            o[r] = (x >= 0.f) ? x : 0.2f * x;
        }
        *reinterpret_cast<f32x4*>(obase + jt * 16 + kg * 4) = o;
    }
}

extern "C" void kernel_launch(void* const* d_in, const int* in_sizes, int n_in,
                              void* d_out, int out_size, void* d_ws, size_t ws_size,
                              hipStream_t stream) {
    const float* src   = (const float*)d_in[0];
    const float* dst   = (const float*)d_in[1];
    const float* a     = (const float*)d_in[2];
    const int*   edges = (const int*)d_in[3];
    float* out = (float*)d_out;

    const size_t wt_bytes = (size_t)NH * NT * ND * ND * sizeof(__bf16);  // 320 KB

    if (ws_size >= wt_bytes) {
        __bf16* wt = (__bf16*)d_ws;
        const int total = NH * ND * ND * NT;
        prep_w_kernel<<<(total + 255) / 256, 256, 0, stream>>>(a, wt);
        mhea_fused<<<512, 256, 0, stream>>>(src, dst, wt, edges, out);
    } else {
        mhea_fused_fallback<<<dim3(NN / 16, NH, NB), 64, 0, stream>>>(
            src, dst, a, edges, out);
    }
}

// Round 16
// 32.844 us; speedup vs baseline: 1.1949x; 1.1949x over previous
//
#include <hip/hip_runtime.h>
#include <hip/hip_bf16.h>

#define NB 16
#define NN 256
#define NH 8
#define ND 64
#define NT 5
#define HD 512   // NH*ND

typedef __bf16 bf16x8 __attribute__((ext_vector_type(8)));
typedef __bf16 bf16x4 __attribute__((ext_vector_type(4)));
typedef float  f32x4  __attribute__((ext_vector_type(4)));
typedef int    i32x4  __attribute__((ext_vector_type(4)));

__device__ __forceinline__ bf16x8 cvt8(f32x4 a, f32x4 b) {
    bf16x8 r;
    r[0] = (__bf16)a[0]; r[1] = (__bf16)a[1]; r[2] = (__bf16)a[2]; r[3] = (__bf16)a[3];
    r[4] = (__bf16)b[0]; r[5] = (__bf16)b[1]; r[6] = (__bf16)b[2]; r[7] = (__bf16)b[3];
    return r;
}

// fire-and-forget global->LDS: lane l writes LDS[base + l*16]; src addr is per-lane.
__device__ __forceinline__ void stage16(const void* g, void* l) {
    __builtin_amdgcn_global_load_lds(
        (const __attribute__((address_space(1))) void*)g,
        (__attribute__((address_space(3))) void*)l,
        16, 0, 0);
}

// Transpose a[(h*64+dd)*64*5 + e*5 + t] (fp32) -> wt[h][t][e][dd] (bf16).
__global__ void prep_w_kernel(const float* __restrict__ a, __bf16* __restrict__ wt) {
    int idx = blockIdx.x * 256 + threadIdx.x;
    if (idx >= NH * ND * ND * NT) return;
    int t  = idx % NT;
    int e  = (idx / NT) % ND;
    int dd = (idx / (NT * ND)) % ND;
    int h  = idx / (NT * ND * ND);
    wt[(((h * NT + t) * ND + e) * ND) + dd] = (__bf16)a[idx];
}

// LDS layout (bytes). W region [0,40960) is reused after prologue.
#define LW   0
#define LS0  40960
#define LS1  45056
#define LS2  0
#define LE0  49152
#define LE1  53248
#define LE2  4096
#define LP0  8192
#define LP1  18432

// ================= fused: block = (b, h, j-quarter); 16 i-tiles =================
// Raw s_barrier + counted vmcnt (m201 pattern): staging stays in flight across
// barriers. S/E triple-buffered (2-iter latency cover); P double-buffered.
__global__ __launch_bounds__(256, 2) void mhea_fused(
    const float* __restrict__ src, const float* __restrict__ dst,
    const __bf16* __restrict__ wt, const int* __restrict__ edges,
    float* __restrict__ out)
{
    __shared__ alignas(16) unsigned char Lb[57344];   // 56 KB

    const int bid = blockIdx.x;
    const int wg  = (bid & 7) * 64 + (bid >> 3);    // XCD-chunked, bijective (512 = 8*64)
    const int b   = wg >> 5;
    const int h   = (wg >> 2) & 7;
    const int jq  = wg & 3;
    const int j0  = jq * 64;

    const int tid = threadIdx.x;
    const int w   = tid >> 6;    // wave 0..3: phase-1 e-tile AND phase-2 j-tile
    const int l   = tid & 63;
    const int il  = l & 15;
    const int kg  = l >> 4;      // lane k-group 0..3

    const int SOFF[3] = {LS0, LS1, LS2};
    const int EOFF[3] = {LE0, LE1, LE2};
    const int POFF[2] = {LP0, LP1};

    // ---------------- prologue ----------------
    // D-frags (fixed per block): dst row j = j0 + w*16 + il (register loads, once).
    bf16x8 cb0, cb1;
    {
        const float* dp = dst + ((size_t)(b * NN + j0 + w * 16 + il)) * HD + h * ND;
        f32x4 q0 = *reinterpret_cast<const f32x4*>(dp + kg * 8);
        f32x4 q1 = *reinterpret_cast<const f32x4*>(dp + kg * 8 + 4);
        f32x4 q2 = *reinterpret_cast<const f32x4*>(dp + 32 + kg * 8);
        f32x4 q3 = *reinterpret_cast<const f32x4*>(dp + 36 + kg * 8);
        cb0 = cvt8(q0, q1);
        cb1 = cvt8(q2, q3);
    }

    // W staging: 40 x 1KB (10/wave), pre-swizzled source.
    {
        const __bf16* wbase = wt + (size_t)(h * NT) * ND * ND;
        __bf16* Wl = (__bf16*)(Lb + LW);
        #pragma unroll
        for (int k = 0; k < 10; ++k) {
            const int idx = w * 10 + k;          // 0..39
            const int t   = idx >> 3;
            const int sub = idx & 7;
            const int e   = sub * 8 + (l >> 3);
            const int c   = (l & 7) ^ (e & 7);
            stage16(wbase + ((size_t)t * ND + e) * ND + c * 8,
                    Wl + t * 4096 + sub * 512);
        }
    }
    // S tiles 0,1 and E tiles 0,1 (1 instr/wave each)
    #pragma unroll
    for (int p = 0; p < 2; ++p) {
        const int row = w * 4 + (l >> 4);
        const int c   = (l & 15) ^ (row & 7);
        stage16(src + ((size_t)(b * NN + p * 16 + row)) * HD + h * ND + c * 4,
                Lb + SOFF[p] + w * 1024);
        stage16(edges + ((size_t)(b * NN + p * 16 + row)) * NN + j0 + c * 4,
                Lb + EOFF[p] + w * 1024);
    }

    asm volatile("s_waitcnt vmcnt(0)" ::: "memory");
    __builtin_amdgcn_sched_barrier(0);
    __builtin_amdgcn_s_barrier();        // W,S0,E0,S1,E1 visible to all waves

    // W-frags -> registers (wave's e-tile = w, all 5 t)
    bf16x8 wa[NT][2];
    {
        const __bf16* Wl = (const __bf16*)(Lb + LW);
        #pragma unroll
        for (int t = 0; t < NT; ++t)
            #pragma unroll
            for (int ks = 0; ks < 2; ++ks)
                wa[t][ks] = *reinterpret_cast<const bf16x8*>(
                    Wl + t * 4096 + (w * 16 + il) * ND + (((ks * 4 + kg) ^ (il & 7)) << 3));
    }
    asm volatile("s_waitcnt lgkmcnt(0)" ::: "memory");
    __builtin_amdgcn_sched_barrier(0);
    __builtin_amdgcn_s_barrier();        // all waves done reading W -> region reusable

    // ---------------- main loop: 16 i-tiles, ONE raw barrier each ----------------
    #pragma unroll
    for (int k = 0; k < 16; ++k) {
        const float* Sc = (const float*)(Lb + SOFF[k % 3]);
        const int*   Ec = (const int*)  (Lb + EOFF[k % 3]);
        __bf16*      Pc = (__bf16*)     (Lb + POFF[k & 1]);

        // a) stage tile k+2 (retired ~2 iters from now; never drained early)
        if (k < 14) {
            const int i2  = (k + 2) * 16;
            const int row = w * 4 + (l >> 4);
            const int c   = (l & 15) ^ (row & 7);
            stage16(src + ((size_t)(b * NN + i2 + row)) * HD + h * ND + c * 4,
                    Lb + SOFF[(k + 2) % 3] + w * 1024);
            stage16(edges + ((size_t)(b * NN + i2 + row)) * NN + j0 + c * 4,
                    Lb + EOFF[(k + 2) % 3] + w * 1024);
        }

        // b) edge int4 for this iter (staged 2 iters ago, retired at barrier k-1)
        const i32x4 ce = *reinterpret_cast<const i32x4*>(
            Ec + il * 64 + (((w * 4 + kg) ^ (il & 7)) << 2));

        // c) phase 1: P_t[i, e-tile w] from S[k%3]
        {
            f32x4 a0 = *reinterpret_cast<const f32x4*>(&Sc[il * ND + (((2 * kg + 0) ^ (il & 7)) << 2)]);
            f32x4 a1 = *reinterpret_cast<const f32x4*>(&Sc[il * ND + (((2 * kg + 1) ^ (il & 7)) << 2)]);
            f32x4 a2 = *reinterpret_cast<const f32x4*>(&Sc[il * ND + (((8 + 2 * kg) ^ (il & 7)) << 2)]);
            f32x4 a3 = *reinterpret_cast<const f32x4*>(&Sc[il * ND + (((9 + 2 * kg) ^ (il & 7)) << 2)]);
            bf16x8 bf0 = cvt8(a0, a1);
            bf16x8 bf1 = cvt8(a2, a3);
            #pragma unroll
            for (int t = 0; t < NT; ++t) {
                // A = W^T rows (m=e), B = src (n=i): lane holds e=w*16+kg*4+r, i=il
                f32x4 pacc = {0.f, 0.f, 0.f, 0.f};
                pacc = __builtin_amdgcn_mfma_f32_16x16x32_bf16(wa[t][0], bf0, pacc, 0, 0, 0);
                pacc = __builtin_amdgcn_mfma_f32_16x16x32_bf16(wa[t][1], bf1, pacc, 0, 0, 0);
                bf16x4 pk;
                pk[0] = (__bf16)pacc[0];
                pk[1] = (__bf16)pacc[1];
                pk[2] = (__bf16)pacc[2];
                pk[3] = (__bf16)pacc[3];
                const int elem = (w * 16 + kg * 4) ^ ((il & 7) << 3);
                *reinterpret_cast<bf16x4*>(Pc + t * 1024 + il * ND + elem) = pk;
            }
        }

        // d) counted-wait barrier: retire stage_{k-1} (cross-wave visibility for
        //    next iter's reads) WITHOUT draining stage_k.
        //    outstanding newer than stage_{k-1}: store_{k-1}(1) + stage_k(2) = 3.
        //    For k>=14 staging stopped: only store_{k-1} is newer -> vmcnt(1).
        if (k < 14) {
            asm volatile("s_waitcnt vmcnt(3) lgkmcnt(0)" ::: "memory");
        } else {
            asm volatile("s_waitcnt vmcnt(1) lgkmcnt(0)" ::: "memory");
        }
        __builtin_amdgcn_sched_barrier(0);
        __builtin_amdgcn_s_barrier();

        // e) phase 2: S_t = dst_rows . P -> select/mask/leaky -> store
        {
            bf16x8 pa[NT][2];
            #pragma unroll
            for (int t = 0; t < NT; ++t)
                #pragma unroll
                for (int ks = 0; ks < 2; ++ks)
                    pa[t][ks] = *reinterpret_cast<const bf16x8*>(
                        Pc + t * 1024 + il * ND + (((ks * 4 + kg) ^ (il & 7)) << 3));

            f32x4 acc[NT];
            #pragma unroll
            for (int t = 0; t < NT; ++t) {
                acc[t] = (f32x4){0.f, 0.f, 0.f, 0.f};
                // A = dst rows (m=j), B = P (n=i): lane holds j=w*16+kg*4+r, i=il
                acc[t] = __builtin_amdgcn_mfma_f32_16x16x32_bf16(cb0, pa[t][0], acc[t], 0, 0, 0);
                acc[t] = __builtin_amdgcn_mfma_f32_16x16x32_bf16(cb1, pa[t][1], acc[t], 0, 0, 0);
            }

            f32x4 o;
            #pragma unroll
            for (int r = 0; r < 4; ++r) {
                const int ev = ce[r];
                float x;
                if (ev < 0) { x = -1e10f; }
                else {
                    x = (ev == 0) ? acc[0][r]
                      : (ev == 1) ? acc[1][r]
                      : (ev == 2) ? acc[2][r]
                      : (ev == 3) ? acc[3][r]
                      :             acc[4][r];
                }
                o[r] = (x >= 0.f) ? x : 0.2f * x;
            }
            *reinterpret_cast<f32x4*>(
                out + ((size_t)(b * NH + h) * NN + k * 16 + il) * NN
                    + j0 + w * 16 + kg * 4) = o;
        }
        // No end-of-iter barrier: next iter's P writes go to the other P buffer;
        // next iter's staging targets a slot whose readers finished before the
        // barrier above (triple-buffer rotation); S/E reads of iter k+1 were
        // retired by this barrier's counted wait.
    }
}

// ---------------- fallback (ws too small): fused 1-wave kernel, araw path ----------------
__global__ __launch_bounds__(64, 3) void mhea_fused_fallback(
    const float* __restrict__ src, const float* __restrict__ dst,
    const float* __restrict__ araw, const int* __restrict__ edges,
    float* __restrict__ out)
{
    __shared__ __bf16 Plds[NT * 16 * 64];

    const int it = blockIdx.x;
    const int h  = blockIdx.y;
    const int b  = blockIdx.z;
    const int i0 = it * 16;

    const int l  = threadIdx.x & 63;
    const int il = l & 15;
    const int kg = l >> 4;

    const float* dbase = dst + (size_t)b * NN * HD + h * ND;
    const int*   erow  = edges + ((size_t)b * NN + i0 + il) * NN;
    const float* sbase = src + (size_t)(b * NN + i0 + il) * HD + h * ND;

    f32x4 s0 = *reinterpret_cast<const f32x4*>(sbase + kg * 8);
    f32x4 s1 = *reinterpret_cast<const f32x4*>(sbase + kg * 8 + 4);
    f32x4 s2 = *reinterpret_cast<const f32x4*>(sbase + 32 + kg * 8);
    f32x4 s3 = *reinterpret_cast<const f32x4*>(sbase + 36 + kg * 8);
    bf16x8 af0 = cvt8(s0, s1);
    bf16x8 af1 = cvt8(s2, s3);

    #pragma unroll
    for (int t = 0; t < NT; ++t) {
        #pragma unroll
        for (int et = 0; et < 4; ++et) {
            bf16x8 w0, w1;
            #pragma unroll
            for (int jj = 0; jj < 8; ++jj) {
                const int ee = et * 16 + il;
                w0[jj] = (__bf16)araw[((size_t)(h * ND + kg * 8 + jj) * ND + ee) * NT + t];
                w1[jj] = (__bf16)araw[((size_t)(h * ND + kg * 8 + jj + 32) * ND + ee) * NT + t];
            }
            f32x4 pacc = {0.f, 0.f, 0.f, 0.f};
            pacc = __builtin_amdgcn_mfma_f32_16x16x32_bf16(w0, af0, pacc, 0, 0, 0);
            pacc = __builtin_amdgcn_mfma_f32_16x16x32_bf16(w1, af1, pacc, 0, 0, 0);
            bf16x4 pk;
            pk[0] = (__bf16)pacc[0];
            pk[1] = (__bf16)pacc[1];
            pk[2] = (__bf16)pacc[2];
            pk[3] = (__bf16)pacc[3];
            const int elem = (et * 16 + kg * 4) ^ ((il & 7) << 3);
            *reinterpret_cast<bf16x4*>(&Plds[t * 1024 + il * 64 + elem]) = pk;
        }
    }

    bf16x8 pa[NT][2];
    #pragma unroll
    for (int t = 0; t < NT; ++t) {
        #pragma unroll
        for (int ks = 0; ks < 2; ++ks) {
            const int elem = (ks * 32 + kg * 8) ^ ((il & 7) << 3);
            pa[t][ks] = *reinterpret_cast<const bf16x8*>(&Plds[t * 1024 + il * 64 + elem]);
        }
    }

    float* obase = out + (((size_t)(b * NH + h)) * NN + i0 + il) * NN;

    for (int jt = 0; jt < 16; ++jt) {
        const float* np = dbase + (size_t)(jt * 16 + il) * HD + kg * 8;
        f32x4 d0 = *reinterpret_cast<const f32x4*>(np);
        f32x4 d1 = *reinterpret_cast<const f32x4*>(np + 4);
        f32x4 d2 = *reinterpret_cast<const f32x4*>(np + 32);
        f32x4 d3 = *reinterpret_cast<const f32x4*>(np + 36);
        i32x4 ce = *reinterpret_cast<const i32x4*>(erow + jt * 16 + kg * 4);
        const bf16x8 cb0 = cvt8(d0, d1);
        const bf16x8 cb1 = cvt8(d2, d3);
        f32x4 acc[NT];
        #pragma unroll
        for (int t = 0; t < NT; ++t) {
            acc[t] = (f32x4){0.f, 0.f, 0.f, 0.f};
            acc[t] = __builtin_amdgcn_mfma_f32_16x16x32_bf16(cb0, pa[t][0], acc[t], 0, 0, 0);
            acc[t] = __builtin_amdgcn_mfma_f32_16x16x32_bf16(cb1, pa[t][1], acc[t], 0, 0, 0);
        }
        f32x4 o;
        #pragma unroll
        for (int r = 0; r < 4; ++r) {
            const int ev = ce[r];
            float x;
            if (ev < 0) { x = -1e10f; }
            else {
                x = (ev == 0) ? acc[0][r]
                  : (ev == 1) ? acc[1][r]
                  : (ev == 2) ? acc[2][r]
                  : (ev == 3) ? acc[3][r]
                  :             acc[4][r];
            }
            o[r] = (x >= 0.f) ? x : 0.2f * x;
        }
        *reinterpret_cast<f32x4*>(obase + jt * 16 + kg * 4) = o;
    }
}

extern "C" void kernel_launch(void* const* d_in, const int* in_sizes, int n_in,
                              void* d_out, int out_size, void* d_ws, size_t ws_size,
                              hipStream_t stream) {
    const float* src   = (const float*)d_in[0];
    const float* dst   = (const float*)d_in[1];
    const float* a     = (const float*)d_in[2];
    const int*   edges = (const int*)d_in[3];
    float* out = (float*)d_out;

    const size_t wt_bytes = (size_t)NH * NT * ND * ND * sizeof(__bf16);  // 320 KB

    if (ws_size >= wt_bytes) {
        __bf16* wt = (__bf16*)d_ws;
        const int total = NH * ND * ND * NT;
        prep_w_kernel<<<(total + 255) / 256, 256, 0, stream>>>(a, wt);
        mhea_fused<<<512, 256, 0, stream>>>(src, dst, wt, edges, out);
    } else {
        mhea_fused_fallback<<<dim3(NN / 16, NH, NB), 64, 0, stream>>>(
            src, dst, a, edges, out);
    }
}

// Round 17
// 27.498 us; speedup vs baseline: 1.4272x; 1.1944x over previous
//
#include <hip/hip_runtime.h>
#include <hip/hip_bf16.h>

#define NB 16
#define NN 256
#define NH 8
#define ND 64
#define NT 5
#define HD 512   // NH*ND

typedef __bf16 bf16x8 __attribute__((ext_vector_type(8)));
typedef __bf16 bf16x4 __attribute__((ext_vector_type(4)));
typedef float  f32x4  __attribute__((ext_vector_type(4)));
typedef int    i32x4  __attribute__((ext_vector_type(4)));

__device__ __forceinline__ bf16x8 cvt8(f32x4 a, f32x4 b) {
    bf16x8 r;
    r[0] = (__bf16)a[0]; r[1] = (__bf16)a[1]; r[2] = (__bf16)a[2]; r[3] = (__bf16)a[3];
    r[4] = (__bf16)b[0]; r[5] = (__bf16)b[1]; r[6] = (__bf16)b[2]; r[7] = (__bf16)b[3];
    return r;
}

// fire-and-forget global->LDS: lane l writes LDS[base + l*16]; src addr is per-lane.
__device__ __forceinline__ void stage16(const void* g, void* l) {
    __builtin_amdgcn_global_load_lds(
        (const __attribute__((address_space(1))) void*)g,
        (__attribute__((address_space(3))) void*)l,
        16, 0, 0);
}

// Transpose a[(h*64+dd)*64*5 + e*5 + t] (fp32) -> wt[h][t][e][dd] (bf16).
__global__ void prep_w_kernel(const float* __restrict__ a, __bf16* __restrict__ wt) {
    int idx = blockIdx.x * 256 + threadIdx.x;
    if (idx >= NH * ND * ND * NT) return;
    int t  = idx % NT;
    int e  = (idx / NT) % ND;
    int dd = (idx / (NT * ND)) % ND;
    int h  = idx / (NT * ND * ND);
    wt[(((h * NT + t) * ND + e) * ND) + dd] = (__bf16)a[idx];
}

// LDS layout (bytes). W region [0,40960) reused after prologue for P0/P1/S2/E2.
#define LW   0
#define LP0  0
#define LP1  10240
#define LS2  20480
#define LE2  24576
#define LS0  40960
#define LS1  45056
#define LE0  49152
#define LE1  57344
// total 65536 (64 KB) -> 2 blocks/CU

// ================= fused: block = (b, h, j-half, i-half); 8 i-tiles =================
// 8 waves: phase-1 wave = (e-tile, t-half); phase-2 wave = 16-j tile of the 128-j half.
// Triple-buffered S/E + counted vmcnt (R16-verified); P double-buffered; 1 barrier/iter.
__global__ __launch_bounds__(512, 2) void mhea_fused(
    const float* __restrict__ src, const float* __restrict__ dst,
    const __bf16* __restrict__ wt, const int* __restrict__ edges,
    float* __restrict__ out)
{
    __shared__ alignas(16) unsigned char Lb[65536];

    const int bid = blockIdx.x;
    const int wg  = (bid & 7) * 64 + (bid >> 3);    // XCD-chunked, bijective (512 = 8*64)
    const int b   = wg >> 5;          // 0..15
    const int h   = (wg >> 2) & 7;
    const int jh  = (wg >> 1) & 1;
    const int ih  = wg & 1;
    const int j0  = jh * 128;
    const int ib0 = ih * 128;

    const int tid = threadIdx.x;
    const int w   = tid >> 6;    // wave 0..7
    const int l   = tid & 63;
    const int il  = l & 15;
    const int kg  = l >> 4;      // lane k-group 0..3

    const int et  = w & 3;       // phase-1 e-tile (0..3)
    const int tl  = w >> 2;      // t-half: 0 -> t{0,1,2}, 1 -> t{3,4}
    const int t0  = tl * 3;
    const int ntl = 3 - tl;      // 3 or 2

    const int SO[3] = {LS0, LS1, LS2};
    const int EO[3] = {LE0, LE1, LE2};

    // ---------------- prologue ----------------
    // D-frags (fixed per block): dst row j = j0 + w*16 + il (register loads, once).
    bf16x8 cb0, cb1;
    {
        const float* dp = dst + ((size_t)(b * NN + j0 + w * 16 + il)) * HD + h * ND;
        f32x4 q0 = *reinterpret_cast<const f32x4*>(dp + kg * 8);
        f32x4 q1 = *reinterpret_cast<const f32x4*>(dp + kg * 8 + 4);
        f32x4 q2 = *reinterpret_cast<const f32x4*>(dp + 32 + kg * 8);
        f32x4 q3 = *reinterpret_cast<const f32x4*>(dp + 36 + kg * 8);
        cb0 = cvt8(q0, q1);
        cb1 = cvt8(q2, q3);
    }

    // W staging: 40 x 1KB (5/wave), pre-swizzled source.
    {
        const __bf16* wbase = wt + (size_t)(h * NT) * ND * ND;
        #pragma unroll
        for (int k = 0; k < 5; ++k) {
            const int idx = w * 5 + k;           // 0..39
            const int t   = idx >> 3;
            const int sub = idx & 7;
            const int e   = sub * 8 + (l >> 3);
            const int c   = (l & 7) ^ (e & 7);
            stage16(wbase + ((size_t)t * ND + e) * ND + c * 8,
                    Lb + LW + t * 8192 + sub * 1024);
        }
    }
    // S tiles 0,1 (4 x 1KB each; waves 0-3, 1 op per tile)
    if (w < 4) {
        #pragma unroll
        for (int p = 0; p < 2; ++p) {
            const int row = w * 4 + (l >> 4);
            const int c   = (l & 15) ^ (row & 7);
            stage16(src + ((size_t)(b * NN + ib0 + p * 16 + row)) * HD + h * ND + c * 4,
                    Lb + SO[p] + w * 1024);
        }
    }
    // E tiles 0,1 (8 x 1KB each; all waves, 1 op per tile). Row = 128 ints = 512B.
    #pragma unroll
    for (int p = 0; p < 2; ++p) {
        const int row = w * 2 + (l >> 5);
        const int c   = (l & 31) ^ (row & 7);
        stage16(edges + ((size_t)(b * NN + ib0 + p * 16 + row)) * NN + j0 + c * 4,
                Lb + EO[p] + w * 1024);
    }

    asm volatile("s_waitcnt vmcnt(0)" ::: "memory");
    __builtin_amdgcn_sched_barrier(0);
    __builtin_amdgcn_s_barrier();        // W, S0/1, E0/1 visible

    // W-frags -> registers (this wave's e-tile, its t-subset)
    bf16x8 wa[3][2];
    #pragma unroll
    for (int tt = 0; tt < 3; ++tt) {
        if (tt < ntl) {
            const int t = t0 + tt;
            #pragma unroll
            for (int ks = 0; ks < 2; ++ks)
                wa[tt][ks] = *reinterpret_cast<const bf16x8*>(
                    Lb + LW + t * 8192 + (et * 16 + il) * 128
                       + (((ks * 4 + kg) ^ (il & 7)) << 4));
        }
    }
    asm volatile("s_waitcnt lgkmcnt(0)" ::: "memory");
    __builtin_amdgcn_sched_barrier(0);
    __builtin_amdgcn_s_barrier();        // W reads done -> region reusable (P/S2/E2)

    // ---------------- main loop: 8 i-tiles, ONE barrier each ----------------
    #pragma unroll
    for (int k = 0; k < 8; ++k) {
        const float* Sc = (const float*)(Lb + SO[k % 3]);
        const int*   Ec = (const int*)  (Lb + EO[k % 3]);
        __bf16*      Pc = (__bf16*)     (Lb + ((k & 1) ? LP1 : LP0));

        // a) stage tile k+2 (retired at barrier k+1 -> ~1.5 iters of cover)
        if (k < 6) {
            const int i2 = ib0 + (k + 2) * 16;
            if (w < 4) {
                const int row = w * 4 + (l >> 4);
                const int c   = (l & 15) ^ (row & 7);
                stage16(src + ((size_t)(b * NN + i2 + row)) * HD + h * ND + c * 4,
                        Lb + SO[(k + 2) % 3] + w * 1024);
            }
            {
                const int row = w * 2 + (l >> 5);
                const int c   = (l & 31) ^ (row & 7);
                stage16(edges + ((size_t)(b * NN + i2 + row)) * NN + j0 + c * 4,
                        Lb + EO[(k + 2) % 3] + w * 1024);
            }
        }

        // b) edge int4 for this iter (tile k staged 2 iters ago, retired at barrier k-1)
        const i32x4 ce = *reinterpret_cast<const i32x4*>(
            Ec + il * 128 + (((w * 4 + kg) ^ (il & 7)) << 2));

        // c) phase 1: P_t[i, e-tile et] for this wave's t-subset
        {
            f32x4 a0 = *reinterpret_cast<const f32x4*>(&Sc[il * ND + (((2 * kg + 0) ^ (il & 7)) << 2)]);
            f32x4 a1 = *reinterpret_cast<const f32x4*>(&Sc[il * ND + (((2 * kg + 1) ^ (il & 7)) << 2)]);
            f32x4 a2 = *reinterpret_cast<const f32x4*>(&Sc[il * ND + (((8 + 2 * kg) ^ (il & 7)) << 2)]);
            f32x4 a3 = *reinterpret_cast<const f32x4*>(&Sc[il * ND + (((9 + 2 * kg) ^ (il & 7)) << 2)]);
            bf16x8 bf0 = cvt8(a0, a1);
            bf16x8 bf1 = cvt8(a2, a3);
            __builtin_amdgcn_s_setprio(1);
            #pragma unroll
            for (int tt = 0; tt < 3; ++tt) {
                if (tt < ntl) {
                    const int t = t0 + tt;
                    // A = W^T rows (m=e), B = src (n=i): lane holds e=et*16+kg*4+r, i=il
                    f32x4 pacc = {0.f, 0.f, 0.f, 0.f};
                    pacc = __builtin_amdgcn_mfma_f32_16x16x32_bf16(wa[tt][0], bf0, pacc, 0, 0, 0);
                    pacc = __builtin_amdgcn_mfma_f32_16x16x32_bf16(wa[tt][1], bf1, pacc, 0, 0, 0);
                    bf16x4 pk;
                    pk[0] = (__bf16)pacc[0];
                    pk[1] = (__bf16)pacc[1];
                    pk[2] = (__bf16)pacc[2];
                    pk[3] = (__bf16)pacc[3];
                    const int elem = (et * 16 + kg * 4) ^ ((il & 7) << 3);
                    *reinterpret_cast<bf16x4*>(Pc + t * 1024 + il * ND + elem) = pk;
                }
            }
            __builtin_amdgcn_s_setprio(0);
        }

        // d) counted-wait barrier (per-wave counts: see derivation in theory)
        if (k < 6) {
            if (w < 4) { asm volatile("s_waitcnt vmcnt(3) lgkmcnt(0)" ::: "memory"); }
            else       { asm volatile("s_waitcnt vmcnt(2) lgkmcnt(0)" ::: "memory"); }
        } else {
            asm volatile("s_waitcnt vmcnt(1) lgkmcnt(0)" ::: "memory");
        }
        __builtin_amdgcn_sched_barrier(0);
        __builtin_amdgcn_s_barrier();

        // e) phase 2: this wave's 16-j tile vs all 16 i of the tile
        {
            bf16x8 pa[NT][2];
            #pragma unroll
            for (int t = 0; t < NT; ++t)
                #pragma unroll
                for (int ks = 0; ks < 2; ++ks)
                    pa[t][ks] = *reinterpret_cast<const bf16x8*>(
                        Pc + t * 1024 + il * ND + (((ks * 4 + kg) ^ (il & 7)) << 3));

            __builtin_amdgcn_s_setprio(1);
            f32x4 acc[NT];
            #pragma unroll
            for (int t = 0; t < NT; ++t) {
                acc[t] = (f32x4){0.f, 0.f, 0.f, 0.f};
                // A = dst rows (m=j), B = P (n=i): lane holds j=w*16+kg*4+r, i=il
                acc[t] = __builtin_amdgcn_mfma_f32_16x16x32_bf16(cb0, pa[t][0], acc[t], 0, 0, 0);
                acc[t] = __builtin_amdgcn_mfma_f32_16x16x32_bf16(cb1, pa[t][1], acc[t], 0, 0, 0);
            }
            __builtin_amdgcn_s_setprio(0);

            f32x4 o;
            #pragma unroll
            for (int r = 0; r < 4; ++r) {
                const int ev = ce[r];
                float x;
                if (ev < 0) { x = -1e10f; }
                else {
                    x = (ev == 0) ? acc[0][r]
                      : (ev == 1) ? acc[1][r]
                      : (ev == 2) ? acc[2][r]
                      : (ev == 3) ? acc[3][r]
                      :             acc[4][r];
                }
                o[r] = (x >= 0.f) ? x : 0.2f * x;
            }
            *reinterpret_cast<f32x4*>(
                out + ((size_t)(b * NH + h) * NN + ib0 + k * 16 + il) * NN
                    + j0 + w * 16 + kg * 4) = o;
        }
        // No trailing barrier: next phase1 writes the OTHER P buffer; S/E slot
        // rotation hazards separated by the barrier above (readers pre-barrier,
        // re-stagers post-barrier); phase2 P-reads drained by next barrier's lgkmcnt(0).
    }
}

// ---------------- fallback (ws too small): fused 1-wave kernel, araw path ----------------
__global__ __launch_bounds__(64, 3) void mhea_fused_fallback(
    const float* __restrict__ src, const float* __restrict__ dst,
    const float* __restrict__ araw, const int* __restrict__ edges,
    float* __restrict__ out)
{
    __shared__ __bf16 Plds[NT * 16 * 64];

    const int it = blockIdx.x;
    const int h  = blockIdx.y;
    const int b  = blockIdx.z;
    const int i0 = it * 16;

    const int l  = threadIdx.x & 63;
    const int il = l & 15;
    const int kg = l >> 4;

    const float* dbase = dst + (size_t)b * NN * HD + h * ND;
    const int*   erow  = edges + ((size_t)b * NN + i0 + il) * NN;
    const float* sbase = src + (size_t)(b * NN + i0 + il) * HD + h * ND;

    f32x4 s0 = *reinterpret_cast<const f32x4*>(sbase + kg * 8);
    f32x4 s1 = *reinterpret_cast<const f32x4*>(sbase + kg * 8 + 4);
    f32x4 s2 = *reinterpret_cast<const f32x4*>(sbase + 32 + kg * 8);
    f32x4 s3 = *reinterpret_cast<const f32x4*>(sbase + 36 + kg * 8);
    bf16x8 af0 = cvt8(s0, s1);
    bf16x8 af1 = cvt8(s2, s3);

    #pragma unroll
    for (int t = 0; t < NT; ++t) {
        #pragma unroll
        for (int et = 0; et < 4; ++et) {
            bf16x8 w0, w1;
            #pragma unroll
            for (int jj = 0; jj < 8; ++jj) {
                const int ee = et * 16 + il;
                w0[jj] = (__bf16)araw[((size_t)(h * ND + kg * 8 + jj) * ND + ee) * NT + t];
                w1[jj] = (__bf16)araw[((size_t)(h * ND + kg * 8 + jj + 32) * ND + ee) * NT + t];
            }
            f32x4 pacc = {0.f, 0.f, 0.f, 0.f};
            pacc = __builtin_amdgcn_mfma_f32_16x16x32_bf16(w0, af0, pacc, 0, 0, 0);
            pacc = __builtin_amdgcn_mfma_f32_16x16x32_bf16(w1, af1, pacc, 0, 0, 0);
            bf16x4 pk;
            pk[0] = (__bf16)pacc[0];
            pk[1] = (__bf16)pacc[1];
            pk[2] = (__bf16)pacc[2];
            pk[3] = (__bf16)pacc[3];
            const int elem = (et * 16 + kg * 4) ^ ((il & 7) << 3);
            *reinterpret_cast<bf16x4*>(&Plds[t * 1024 + il * 64 + elem]) = pk;
        }
    }

    bf16x8 pa[NT][2];
    #pragma unroll
    for (int t = 0; t < NT; ++t) {
        #pragma unroll
        for (int ks = 0; ks < 2; ++ks) {
            const int elem = (ks * 32 + kg * 8) ^ ((il & 7) << 3);
            pa[t][ks] = *reinterpret_cast<const bf16x8*>(&Plds[t * 1024 + il * 64 + elem]);
        }
    }

    float* obase = out + (((size_t)(b * NH + h)) * NN + i0 + il) * NN;

    for (int jt = 0; jt < 16; ++jt) {
        const float* np = dbase + (size_t)(jt * 16 + il) * HD + kg * 8;
        f32x4 d0 = *reinterpret_cast<const f32x4*>(np);
        f32x4 d1 = *reinterpret_cast<const f32x4*>(np + 4);
        f32x4 d2 = *reinterpret_cast<const f32x4*>(np + 32);
        f32x4 d3 = *reinterpret_cast<const f32x4*>(np + 36);
        i32x4 ce = *reinterpret_cast<const i32x4*>(erow + jt * 16 + kg * 4);
        const bf16x8 cb0 = cvt8(d0, d1);
        const bf16x8 cb1 = cvt8(d2, d3);
        f32x4 acc[NT];
        #pragma unroll
        for (int t = 0; t < NT; ++t) {
            acc[t] = (f32x4){0.f, 0.f, 0.f, 0.f};
            acc[t] = __builtin_amdgcn_mfma_f32_16x16x32_bf16(cb0, pa[t][0], acc[t], 0, 0, 0);
            acc[t] = __builtin_amdgcn_mfma_f32_16x16x32_bf16(cb1, pa[t][1], acc[t], 0, 0, 0);
        }
        f32x4 o;
        #pragma unroll
        for (int r = 0; r < 4; ++r) {
            const int ev = ce[r];
            float x;
            if (ev < 0) { x = -1e10f; }
            else {
                x = (ev == 0) ? acc[0][r]
                  : (ev == 1) ? acc[1][r]
                  : (ev == 2) ? acc[2][r]
                  : (ev == 3) ? acc[3][r]
                  :             acc[4][r];
            }
            o[r] = (x >= 0.f) ? x : 0.2f * x;
        }
        *reinterpret_cast<f32x4*>(obase + jt * 16 + kg * 4) = o;
    }
}

extern "C" void kernel_launch(void* const* d_in, const int* in_sizes, int n_in,
                              void* d_out, int out_size, void* d_ws, size_t ws_size,
                              hipStream_t stream) {
    const float* src   = (const float*)d_in[0];
    const float* dst   = (const float*)d_in[1];
    const float* a     = (const float*)d_in[2];
    const int*   edges = (const int*)d_in[3];
    float* out = (float*)d_out;

    const size_t wt_bytes = (size_t)NH * NT * ND * ND * sizeof(__bf16);  // 320 KB

    if (ws_size >= wt_bytes) {
        __bf16* wt = (__bf16*)d_ws;
        const int total = NH * ND * ND * NT;
        prep_w_kernel<<<(total + 255) / 256, 256, 0, stream>>>(a, wt);
        mhea_fused<<<512, 512, 0, stream>>>(src, dst, wt, edges, out);
    } else {
        mhea_fused_fallback<<<dim3(NN / 16, NH, NB), 64, 0, stream>>>(
            src, dst, a, edges, out);
    }
}